// Round 14
// baseline (121.888 us; speedup 1.0000x reference)
//
#include <hip/hip_runtime.h>
#include <math.h>

#define EPS 1e-5f

typedef __attribute__((ext_vector_type(8))) short short8v;
typedef __attribute__((ext_vector_type(4))) float f32x4;

// ---- bf16 split helpers (RNE) ----
__device__ __forceinline__ unsigned short bf16r(float x) {
    unsigned u = __float_as_uint(x);
    return (unsigned short)((u + 0x7FFFu + ((u >> 16) & 1u)) >> 16);
}
__device__ __forceinline__ float bf2f(unsigned short h) {
    return __uint_as_float(((unsigned)h) << 16);
}
// force a wave-uniform float into an SGPR (exact when value is uniform)
__device__ __forceinline__ float sgpr_pin(float x) {
    return __uint_as_float(__builtin_amdgcn_readfirstlane(__float_as_uint(x)));
}

// ---- DPP quad-reduction helpers ----
__device__ __forceinline__ float dpp_xor1_max(float x) {
    int xi = __float_as_int(x);
    int yi = __builtin_amdgcn_update_dpp(xi, xi, 0xB1, 0xF, 0xF, true);
    return fmaxf(x, __int_as_float(yi));
}
__device__ __forceinline__ float dpp_xor2_max(float x) {
    int xi = __float_as_int(x);
    int yi = __builtin_amdgcn_update_dpp(xi, xi, 0x4E, 0xF, 0xF, true);
    return fmaxf(x, __int_as_float(yi));
}

// ---------------------------------------------------------------------------
// k_pre (66 blocks): Bpack (conv3 bf16-split B), w2q/bias2 (conv2 fold),
// cTab4/qTab4 (edge fold), bias3, sf1/cf1, sf2/cf2.
// ---------------------------------------------------------------------------
__global__ __launch_bounds__(256) void k_pre(
    const float* __restrict__ w3, const float* __restrict__ b3,
    const float* __restrict__ g3, const float* __restrict__ be3,
    const float* __restrict__ m3, const float* __restrict__ v3,
    const float* __restrict__ w2, const float* __restrict__ b2,
    const float* __restrict__ g2, const float* __restrict__ be2,
    const float* __restrict__ m2, const float* __restrict__ v2,
    const float* __restrict__ w_info, const float* __restrict__ b_info,
    const float* __restrict__ g_info, const float* __restrict__ be_info,
    const float* __restrict__ m_info, const float* __restrict__ v_info,
    const float* __restrict__ bf1, const float* __restrict__ gf1,
    const float* __restrict__ bef1, const float* __restrict__ mf1,
    const float* __restrict__ vf1,
    const float* __restrict__ bf2, const float* __restrict__ gf2,
    const float* __restrict__ bef2, const float* __restrict__ mf2,
    const float* __restrict__ vf2,
    unsigned short* __restrict__ Bh, unsigned short* __restrict__ Bl,
    float* __restrict__ bias3,
    float4* __restrict__ w2q, float* __restrict__ bias2,
    float4* __restrict__ cTab4, float4* __restrict__ qTab4,
    float* __restrict__ sf1, float* __restrict__ cf1,
    float* __restrict__ sf2, float* __restrict__ cf2)
{
    const int blk = blockIdx.x, tid = threadIdx.x;
    if (blk < 64) {
        const int t = blk * 256 + tid;        // (kt,nt,lane)
        const int kt = t >> 12;
        const int nt = (t >> 6) & 63;
        const int lane = t & 63;
        const int o  = nt * 16 + (lane & 15);
        const int kb = kt * 32 + ((lane >> 4) << 3);
        const float a3 = g3[o] * rsqrtf(v3[o] + EPS);
        unsigned short hi[8], lo[8];
        #pragma unroll
        for (int j = 0; j < 8; ++j) {
            const float wv = a3 * w3[(size_t)o * 128 + kb + j];
            hi[j] = bf16r(wv);
            lo[j] = bf16r(wv - bf2f(hi[j]));
        }
        #pragma unroll
        for (int j = 0; j < 8; ++j) {
            Bh[(size_t)t * 8 + j] = hi[j];
            Bl[(size_t)t * 8 + j] = lo[j];
        }
    } else if (blk == 64) {
        for (int idx = tid; idx < 2048; idx += 256) {
            const int o2 = idx & 127, cq = idx >> 7;
            const float a2 = g2[o2] * rsqrtf(v2[o2] + EPS);
            const float4 w = *(const float4*)(w2 + (size_t)o2 * 64 + cq * 4);
            w2q[cq * 128 + o2] = make_float4(a2 * w.x, a2 * w.y, a2 * w.z, a2 * w.w);
        }
        if (tid < 128) {
            const float a2 = g2[tid] * rsqrtf(v2[tid] + EPS);
            bias2[tid] = a2 * (b2[tid] - m2[tid]) + be2[tid];
        }
    } else {
        if (tid < 64) {
            const int o = tid;
            const float w0 = w_info[o*6+0], w1 = w_info[o*6+1], w2c = w_info[o*6+2];
            const float w3c = w_info[o*6+3], w4 = w_info[o*6+4], w5 = w_info[o*6+5];
            const float a = g_info[o] * rsqrtf(v_info[o] + EPS);
            cTab4[o] = make_float4(a*w0, a*w1, a*w2c, 0.f);
            qTab4[o] = make_float4(a*(w3c-w0), a*(w4-w1), a*(w5-w2c),
                                   a*(b_info[o]-m_info[o]) + be_info[o]);
        }
        for (int c = tid; c < 1024; c += 256) {
            const float a3 = g3[c] * rsqrtf(v3[c] + EPS);
            bias3[c] = a3 * (b3[c] - m3[c]) + be3[c];
        }
        for (int c = tid; c < 512; c += 256) {
            const float s = gf1[c] * rsqrtf(vf1[c] + EPS);
            sf1[c] = s;
            cf1[c] = s * (bf1[c] - mf1[c]) + bef1[c];
        }
        {
            const int c = tid;
            const float s = gf2[c] * rsqrtf(vf2[c] + EPS);
            sf2[c] = s;
            cf2[c] = s * (bf2[c] - mf2[c]) + bef2[c];
        }
    }
}

// ---------------------------------------------------------------------------
// k_edge1b: FUSED edge-conv (6->64) + BN + ReLU + full max over K=520 +
// conv2 (64->128) + BN + ReLU + bf16 hi/lo split for MFMA.
// ONE BLOCK PER b, 1024 thr; wave = n, lane = k-slot.
// R12 lesson: three spill-hint fixes failed; the allocator pins 1024-thr
// blocks at <=64 VGPRs.  RESTRUCTURE so the ceiling is unreachable:
// o-tiles of EIGHT -> live state = acc[8] + temps ~ 16 VGPRs.  8 LDS
// passes instead of 4 (LDS pipe ~7us, overlapped with ~7us VALU).
// ---------------------------------------------------------------------------
__global__ __launch_bounds__(1024) void k_edge1b(
    const float* __restrict__ pts,        // [256,15,3]
    const float* __restrict__ info,       // [256,520,15,3]
    const float4* __restrict__ cTab4,     // [64]
    const float4* __restrict__ qTab4,     // [64]
    const float4* __restrict__ w2q,       // [16][128]
    const float* __restrict__ bias2,      // [128]
    unsigned short* __restrict__ h2h,     // [256][16][128] bf16 hi
    unsigned short* __restrict__ h2l)     // [256][16][128] bf16 lo
{
    __shared__ float ds[23400];           // 93600 B
    __shared__ float part[15][8][17];     // 8160 B
    __shared__ float h1s[960];            // 3840 B   (total 105600 B)

    const int tid = threadIdx.x;
    const int b = blockIdx.x;

    { // coalesced staging of the full 520 k-rows for this b
        const float4* src = (const float4*)(info + (size_t)b * 23400);
        float4* dst = (float4*)ds;
        for (int i = tid; i < 5850; i += 1024) dst[i] = src[i];
    }
    __syncthreads();

    const int wave = tid >> 6, lane = tid & 63;
    if (wave < 15) {
        const int n = wave;
        const float x0 = pts[b*45 + n*3 + 0];
        const float x1 = pts[b*45 + n*3 + 1];
        const float x2 = pts[b*45 + n*3 + 2];

        #pragma unroll 1
        for (int t = 0; t < 8; ++t) {     // o-tiles of 8, sequential
            // coefficients pinned to SGPRs (wave-uniform, exact)
            float c0[8], c1[8], c2[8];
            #pragma unroll
            for (int j = 0; j < 8; ++j) {
                const float4 cv = cTab4[t*8 + j];
                c0[j] = sgpr_pin(cv.x);
                c1[j] = sgpr_pin(cv.y);
                c2[j] = sgpr_pin(cv.z);
            }
            float acc[8];
            #pragma unroll
            for (int j = 0; j < 8; ++j) acc[j] = -INFINITY;

            for (int kk = lane; kk < 520; kk += 64) {
                const float* p = ds + kk*45 + n*3;       // per-lane LDS read
                const float d0 = p[0], d1 = p[1], d2 = p[2];
                #pragma unroll
                for (int j = 0; j < 8; ++j)
                    acc[j] = fmaxf(acc[j],
                        fmaf(c0[j], d0, fmaf(c1[j], d1, c2[j] * d2)));
            }
            #pragma unroll
            for (int j = 0; j < 8; ++j) {
                acc[j] = dpp_xor1_max(acc[j]);
                acc[j] = dpp_xor2_max(acc[j]);
            }
            // stage A: each lane writes 2 slots (o = 4i+r4, quad q4)
            const int q4 = lane >> 2, r4 = lane & 3;
            #pragma unroll
            for (int i = 0; i < 2; ++i) {
                float v = acc[4*i];
                v = (r4 == 1) ? acc[4*i+1] : v;
                v = (r4 == 2) ? acc[4*i+2] : v;
                v = (r4 == 3) ? acc[4*i+3] : v;
                part[n][4*i + r4][q4] = v;
            }
            __builtin_amdgcn_sched_barrier(0);
            asm volatile("s_waitcnt lgkmcnt(0)" ::: "memory");
            __builtin_amdgcn_sched_barrier(0);
            // stage B: lanes 0..31, 4 lanes per o, gather 16 quads
            const int o4 = (lane >> 2) & 7, j4 = lane & 3;
            float m =          part[n][o4][4*j4 + 0];
            m = fmaxf(m, part[n][o4][4*j4 + 1]);
            m = fmaxf(m, part[n][o4][4*j4 + 2]);
            m = fmaxf(m, part[n][o4][4*j4 + 3]);
            m = dpp_xor1_max(m);
            m = dpp_xor2_max(m);
            if (j4 == 0 && lane < 32) {
                // bias applied here (k-invariant, hoisted)
                const float4 qv = qTab4[t*8 + o4];
                const float bias = fmaf(qv.x, x0, fmaf(qv.y, x1,
                                   fmaf(qv.z, x2, qv.w)));
                h1s[n*64 + t*8 + o4] = fmaxf(m + bias, 0.f);
            }
            __builtin_amdgcn_sched_barrier(0);
            asm volatile("s_waitcnt lgkmcnt(0)" ::: "memory");
            __builtin_amdgcn_sched_barrier(0);
        }
    }
    __syncthreads();

    // conv2: 16x128 outputs (row 15 = pad 0), bf16 hi/lo split write
    for (int idx = tid; idx < 2048; idx += 1024) {
        const int o2 = idx & 127, n = idx >> 7;   // n: 0..15
        float val = 0.f;
        if (n < 15) {
            float acc = 0.f;
            #pragma unroll
            for (int cq = 0; cq < 16; ++cq) {
                const float4 h4 = *(const float4*)(&h1s[n*64 + cq*4]);
                const float4 w4 = w2q[cq*128 + o2];
                acc = fmaf(w4.x, h4.x, fmaf(w4.y, h4.y,
                      fmaf(w4.z, h4.z, fmaf(w4.w, h4.w, acc))));
            }
            val = fmaxf(acc + bias2[o2], 0.f);
        }
        const unsigned short hi = bf16r(val);
        const unsigned short lo = bf16r(val - bf2f(hi));
        h2h[(size_t)b*2048 + n*128 + o2] = hi;
        h2l[(size_t)b*2048 + n*128 + o2] = lo;
    }
}

// ---------------------------------------------------------------------------
// k_s3: conv3 via bf16x3-split MFMA + global max over N=15.  (validated R9)
// ---------------------------------------------------------------------------
__global__ __launch_bounds__(256) void k_s3(
    const unsigned short* __restrict__ h2h,
    const unsigned short* __restrict__ h2l,
    const unsigned short* __restrict__ Bh,
    const unsigned short* __restrict__ Bl,
    const float* __restrict__ bias3,
    float* __restrict__ gout)         // [256,1024]
{
    const int tid = threadIdx.x;
    const int b = blockIdx.x;
    const int wave = tid >> 6, lane = tid & 63;
    const int arow = lane & 15, agrp = lane >> 4;

    short8v ahi[4], alo[4];
    {
        const unsigned short* Ab = h2h + (size_t)b*2048 + arow*128 + agrp*8;
        const unsigned short* Al = h2l + (size_t)b*2048 + arow*128 + agrp*8;
        #pragma unroll
        for (int kt = 0; kt < 4; ++kt) {
            ahi[kt] = *(const short8v*)(Ab + kt*32);
            alo[kt] = *(const short8v*)(Al + kt*32);
        }
    }

    for (int ntl = 0; ntl < 16; ++ntl) {
        const int nt = wave * 16 + ntl;
        f32x4 a0 = {0.f, 0.f, 0.f, 0.f};
        f32x4 a1 = a0, a2 = a0;
        #pragma unroll
        for (int kt = 0; kt < 4; ++kt) {
            const size_t off = (((size_t)kt*64 + nt)*64 + lane) * 8;
            const short8v bh = *(const short8v*)(Bh + off);
            const short8v bl = *(const short8v*)(Bl + off);
            a0 = __builtin_amdgcn_mfma_f32_16x16x32_bf16(ahi[kt], bh, a0, 0, 0, 0);
            a1 = __builtin_amdgcn_mfma_f32_16x16x32_bf16(ahi[kt], bl, a1, 0, 0, 0);
            a2 = __builtin_amdgcn_mfma_f32_16x16x32_bf16(alo[kt], bh, a2, 0, 0, 0);
        }
        const float r0 = a0[0] + a1[0] + a2[0];
        const float r1 = a0[1] + a1[1] + a2[1];
        const float r2 = a0[2] + a1[2] + a2[2];
        const float r3 = a0[3] + a1[3] + a2[3];
        float m = fmaxf(fmaxf(r0, r1), r2);
        if (agrp != 3) m = fmaxf(m, r3);          // exclude pad row 15
        m = fmaxf(m, __shfl_xor(m, 16));
        m = fmaxf(m, __shfl_xor(m, 32));
        if (lane < 16)
            gout[(size_t)b*1024 + nt*16 + lane] = m + bias3[nt*16 + lane];
    }
}

// ---------------------------------------------------------------------------
// k_fc1p: fc1 split-K=2 raw partials.  grid (8,16,2), 32x32 tile.
// ---------------------------------------------------------------------------
__global__ __launch_bounds__(256) void k_fc1p(
    const float* __restrict__ A,      // g [256][1024]
    const float* __restrict__ W,      // wf1 [512][1024]
    float* __restrict__ P)            // [2][256][512]
{
    __shared__ float As[32][36];
    __shared__ float Ws[32][36];

    const int tid = threadIdx.x;
    const int bm = blockIdx.x * 32, bn = blockIdx.y * 32;
    const int ks = blockIdx.z;
    const int ml = (tid >> 4) * 2, nl = (tid & 15) * 2;
    const int row = tid >> 3, kq = (tid & 7) * 4;

    float acc00 = 0.f, acc01 = 0.f, acc10 = 0.f, acc11 = 0.f;

    for (int k0 = 0; k0 < 512; k0 += 32) {
        const int ch = ks * 512 + k0 + kq;
        const float4 av = *(const float4*)(A + (size_t)(bm + row) * 1024 + ch);
        const float4 wv = *(const float4*)(W + (size_t)(bn + row) * 1024 + ch);
        __syncthreads();
        *(float4*)(&As[row][kq]) = av;
        *(float4*)(&Ws[row][kq]) = wv;
        __syncthreads();
        const float4* a0p = (const float4*)(&As[ml][0]);
        const float4* a1p = (const float4*)(&As[ml + 1][0]);
        const float4* b0p = (const float4*)(&Ws[nl][0]);
        const float4* b1p = (const float4*)(&Ws[nl + 1][0]);
        #pragma unroll
        for (int q = 0; q < 8; ++q) {
            const float4 a0 = a0p[q], a1 = a1p[q], b0 = b0p[q], b1 = b1p[q];
            acc00 = fmaf(a0.x, b0.x, fmaf(a0.y, b0.y, fmaf(a0.z, b0.z, fmaf(a0.w, b0.w, acc00))));
            acc01 = fmaf(a0.x, b1.x, fmaf(a0.y, b1.y, fmaf(a0.z, b1.z, fmaf(a0.w, b1.w, acc01))));
            acc10 = fmaf(a1.x, b0.x, fmaf(a1.y, b0.y, fmaf(a1.z, b0.z, fmaf(a1.w, b0.w, acc10))));
            acc11 = fmaf(a1.x, b1.x, fmaf(a1.y, b1.y, fmaf(a1.z, b1.z, fmaf(a1.w, b1.w, acc11))));
        }
    }
    float* p0 = P + (size_t)ks * 131072 + (size_t)(bm + ml) * 512 + bn + nl;
    p0[0] = acc00; p0[1] = acc01;
    float* p1 = p0 + 512;
    p1[0] = acc10; p1[1] = acc11;
}

// ---------------------------------------------------------------------------
// k_fc2p: fc2 split-K=2; A-tile finishes f1 (BN+ReLU+combine) on the fly.
// ---------------------------------------------------------------------------
__global__ __launch_bounds__(256) void k_fc2p(
    const float* __restrict__ fp,     // [2][256][512]
    const float* __restrict__ sf1, const float* __restrict__ cf1,
    const float* __restrict__ W,      // wf2 [256][512]
    float* __restrict__ P2)           // [2][256][256]
{
    __shared__ float As[32][36];
    __shared__ float Ws[32][36];

    const int tid = threadIdx.x;
    const int bm = blockIdx.x * 32, bn = blockIdx.y * 32;
    const int ks = blockIdx.z;
    const int ml = (tid >> 4) * 2, nl = (tid & 15) * 2;
    const int row = tid >> 3, kq = (tid & 7) * 4;

    float acc00 = 0.f, acc01 = 0.f, acc10 = 0.f, acc11 = 0.f;

    for (int k0 = 0; k0 < 256; k0 += 32) {
        const int ch = ks * 256 + k0 + kq;
        const float4 p0 = *(const float4*)(fp + (size_t)(bm + row) * 512 + ch);
        const float4 p1 = *(const float4*)(fp + 131072 + (size_t)(bm + row) * 512 + ch);
        const float4 s4 = *(const float4*)(sf1 + ch);
        const float4 c4 = *(const float4*)(cf1 + ch);
        float4 av;
        av.x = fmaxf(fmaf(s4.x, p0.x + p1.x, c4.x), 0.f);
        av.y = fmaxf(fmaf(s4.y, p0.y + p1.y, c4.y), 0.f);
        av.z = fmaxf(fmaf(s4.z, p0.z + p1.z, c4.z), 0.f);
        av.w = fmaxf(fmaf(s4.w, p0.w + p1.w, c4.w), 0.f);
        const float4 wv = *(const float4*)(W + (size_t)(bn + row) * 512 + ch);
        __syncthreads();
        *(float4*)(&As[row][kq]) = av;
        *(float4*)(&Ws[row][kq]) = wv;
        __syncthreads();
        const float4* a0p = (const float4*)(&As[ml][0]);
        const float4* a1p = (const float4*)(&As[ml + 1][0]);
        const float4* b0p = (const float4*)(&Ws[nl][0]);
        const float4* b1p = (const float4*)(&Ws[nl + 1][0]);
        #pragma unroll
        for (int q = 0; q < 8; ++q) {
            const float4 a0 = a0p[q], a1 = a1p[q], b0 = b0p[q], b1 = b1p[q];
            acc00 = fmaf(a0.x, b0.x, fmaf(a0.y, b0.y, fmaf(a0.z, b0.z, fmaf(a0.w, b0.w, acc00))));
            acc01 = fmaf(a0.x, b1.x, fmaf(a0.y, b1.y, fmaf(a0.z, b1.z, fmaf(a0.w, b1.w, acc01))));
            acc10 = fmaf(a1.x, b0.x, fmaf(a1.y, b0.y, fmaf(a1.z, b0.z, fmaf(a1.w, b0.w, acc10))));
            acc11 = fmaf(a1.x, b1.x, fmaf(a1.y, b1.y, fmaf(a1.z, b1.z, fmaf(a1.w, b1.w, acc11))));
        }
    }
    float* q0 = P2 + (size_t)ks * 65536 + (size_t)(bm + ml) * 256 + bn + nl;
    q0[0] = acc00; q0[1] = acc01;
    float* q1 = q0 + 256;
    q1[0] = acc10; q1[1] = acc11;
}

// ---------------------------------------------------------------------------
// k_ep2: f2 = relu(sf2*(P2[0]+P2[1]) + cf2)
// ---------------------------------------------------------------------------
__global__ __launch_bounds__(256) void k_ep2(
    const float* __restrict__ P2, const float* __restrict__ sf2,
    const float* __restrict__ cf2, float* __restrict__ f2)
{
    const int i = blockIdx.x * 256 + threadIdx.x;
    const int n = i & 255;
    const float v = P2[i] + P2[65536 + i];
    f2[i] = fmaxf(fmaf(sf2[n], v, cf2[n]), 0.f);
}

// ---------------------------------------------------------------------------
// k_fc3: C = A*W^T + bias
// ---------------------------------------------------------------------------
__global__ __launch_bounds__(256) void k_fc3(
    const float* __restrict__ A, const float* __restrict__ W,
    const float* __restrict__ bias, float* __restrict__ C, int K, int Nc)
{
    __shared__ float As[32][36];
    __shared__ float Ws[32][36];

    const int tid = threadIdx.x;
    const int bm = blockIdx.x * 32, bn = blockIdx.y * 32;
    const int ml = (tid >> 4) * 2, nl = (tid & 15) * 2;
    const int row = tid >> 3, kq = (tid & 7) * 4;

    float acc00 = 0.f, acc01 = 0.f, acc10 = 0.f, acc11 = 0.f;

    for (int k0 = 0; k0 < K; k0 += 32) {
        const float4 av = *(const float4*)(A + (size_t)(bm + row) * K + k0 + kq);
        const float4 wv = *(const float4*)(W + (size_t)(bn + row) * K + k0 + kq);
        __syncthreads();
        *(float4*)(&As[row][kq]) = av;
        *(float4*)(&Ws[row][kq]) = wv;
        __syncthreads();
        const float4* a0p = (const float4*)(&As[ml][0]);
        const float4* a1p = (const float4*)(&As[ml + 1][0]);
        const float4* b0p = (const float4*)(&Ws[nl][0]);
        const float4* b1p = (const float4*)(&Ws[nl + 1][0]);
        #pragma unroll
        for (int q = 0; q < 8; ++q) {
            const float4 a0 = a0p[q], a1 = a1p[q], b0 = b0p[q], b1 = b1p[q];
            acc00 = fmaf(a0.x, b0.x, fmaf(a0.y, b0.y, fmaf(a0.z, b0.z, fmaf(a0.w, b0.w, acc00))));
            acc01 = fmaf(a0.x, b1.x, fmaf(a0.y, b1.y, fmaf(a0.z, b1.z, fmaf(a0.w, b1.w, acc01))));
            acc10 = fmaf(a1.x, b0.x, fmaf(a1.y, b0.y, fmaf(a1.z, b0.z, fmaf(a1.w, b0.w, acc10))));
            acc11 = fmaf(a1.x, b1.x, fmaf(a1.y, b1.y, fmaf(a1.z, b1.z, fmaf(a1.w, b1.w, acc11))));
        }
    }

    const int n0 = bn + nl, n1 = n0 + 1;
    float* cr0 = C + (size_t)(bm + ml) * Nc + n0;
    cr0[0] = acc00 + bias[n0]; cr0[1] = acc01 + bias[n1];
    float* cr1 = C + (size_t)(bm + ml + 1) * Nc + n0;
    cr1[0] = acc10 + bias[n0]; cr1[1] = acc11 + bias[n1];
}

// ---------------------------------------------------------------------------
extern "C" void kernel_launch(void* const* d_in, const int* in_sizes, int n_in,
                              void* d_out, int out_size, void* d_ws, size_t ws_size,
                              hipStream_t stream)
{
    const float* pts     = (const float*)d_in[0];
    const float* info    = (const float*)d_in[2];
    const float* w_info  = (const float*)d_in[3];
    const float* b_info  = (const float*)d_in[4];
    const float* g_info  = (const float*)d_in[5];
    const float* be_info = (const float*)d_in[6];
    const float* m_info  = (const float*)d_in[7];
    const float* v_info  = (const float*)d_in[8];
    const float* w2      = (const float*)d_in[9];
    const float* b2      = (const float*)d_in[10];
    const float* g2      = (const float*)d_in[11];
    const float* be2     = (const float*)d_in[12];
    const float* m2      = (const float*)d_in[13];
    const float* v2      = (const float*)d_in[14];
    const float* w3      = (const float*)d_in[15];
    const float* b3      = (const float*)d_in[16];
    const float* g3      = (const float*)d_in[17];
    const float* be3     = (const float*)d_in[18];
    const float* m3      = (const float*)d_in[19];
    const float* v3      = (const float*)d_in[20];
    const float* wf1     = (const float*)d_in[21];
    const float* bf1     = (const float*)d_in[22];
    const float* gf1     = (const float*)d_in[23];
    const float* bef1    = (const float*)d_in[24];
    const float* mf1     = (const float*)d_in[25];
    const float* vf1     = (const float*)d_in[26];
    const float* wf2     = (const float*)d_in[27];
    const float* bf2     = (const float*)d_in[28];
    const float* gf2     = (const float*)d_in[29];
    const float* bef2    = (const float*)d_in[30];
    const float* mf2     = (const float*)d_in[31];
    const float* vf2     = (const float*)d_in[32];
    const float* wf3     = (const float*)d_in[33];
    const float* bf3     = (const float*)d_in[34];

    float* ws = (float*)d_ws;
    unsigned short* h2h   = (unsigned short*)(ws + 491520);      // 524288 bf16
    unsigned short* h2l   = (unsigned short*)(ws + 753664);      // 524288 bf16
    float*          g     = ws + 1015808;                        // 262144
    unsigned short* Bh    = (unsigned short*)(ws + 1277952);     // 131072 bf16
    unsigned short* Bl    = (unsigned short*)(ws + 1343488);     // 131072 bf16
    float*          bias3 = ws + 1409024;                        // 1024
    float4*         w2q   = (float4*)(ws + 1410048);             // 8192
    float*          bias2 = ws + 1418240;                        // 128
    float4*         cTab4 = (float4*)(ws + 1418368);             // 256
    float4*         qTab4 = (float4*)(ws + 1418624);             // 256
    float*          sf1   = ws + 1418880;                        // 512
    float*          cf1   = ws + 1419392;                        // 512
    float*          sf2   = ws + 1419904;                        // 256
    float*          cf2   = ws + 1420160;                        // 256
    float*          fp    = ws;                                  // [2][256][512] (free region)
    float*          P2    = ws + 262144;                         // [2][256][256]

    float* ret = (float*)d_out;            // [256, 800]
    float* f2  = ret + 256 * 800;          // [256, 256]

    k_pre<<<66, 256, 0, stream>>>(
        w3, b3, g3, be3, m3, v3,
        w2, b2, g2, be2, m2, v2,
        w_info, b_info, g_info, be_info, m_info, v_info,
        bf1, gf1, bef1, mf1, vf1,
        bf2, gf2, bef2, mf2, vf2,
        Bh, Bl, bias3, w2q, bias2, cTab4, qTab4, sf1, cf1, sf2, cf2);

    k_edge1b<<<256, 1024, 0, stream>>>(pts, info, cTab4, qTab4,
                                       w2q, bias2, h2h, h2l);

    k_s3<<<256, 256, 0, stream>>>(h2h, h2l, Bh, Bl, bias3, g);

    k_fc1p<<<dim3(8, 16, 2), 256, 0, stream>>>(g, wf1, fp);

    k_fc2p<<<dim3(8, 8, 2), 256, 0, stream>>>(fp, sf1, cf1, wf2, P2);

    k_ep2<<<256, 256, 0, stream>>>(P2, sf2, cf2, f2);

    k_fc3<<<dim3(8, 25), 256, 0, stream>>>(f2, wf3, bf3, ret, 256, 800);
}

// Round 16
// 112.847 us; speedup vs baseline: 1.0801x; 1.0801x over previous
//
#include <hip/hip_runtime.h>
#include <math.h>

#define EPS 1e-5f

typedef __attribute__((ext_vector_type(8))) short short8v;
typedef __attribute__((ext_vector_type(4))) float f32x4;

// ---- bf16 split helpers (RNE) ----
__device__ __forceinline__ unsigned short bf16r(float x) {
    unsigned u = __float_as_uint(x);
    return (unsigned short)((u + 0x7FFFu + ((u >> 16) & 1u)) >> 16);
}
__device__ __forceinline__ float bf2f(unsigned short h) {
    return __uint_as_float(((unsigned)h) << 16);
}

// ---------------------------------------------------------------------------
// k_pre (66 blocks): Bpack (conv3 bf16-split B), w2q/bias2 (conv2 fold),
// Bedge (edge-conv MFMA B-frags, bf16x3 packed into one K=32 via slots 0-8),
// qTab4 (edge bias fold), bias3, sf1/cf1, sf2/cf2.
// ---------------------------------------------------------------------------
__global__ __launch_bounds__(256) void k_pre(
    const float* __restrict__ w3, const float* __restrict__ b3,
    const float* __restrict__ g3, const float* __restrict__ be3,
    const float* __restrict__ m3, const float* __restrict__ v3,
    const float* __restrict__ w2, const float* __restrict__ b2,
    const float* __restrict__ g2, const float* __restrict__ be2,
    const float* __restrict__ m2, const float* __restrict__ v2,
    const float* __restrict__ w_info, const float* __restrict__ b_info,
    const float* __restrict__ g_info, const float* __restrict__ be_info,
    const float* __restrict__ m_info, const float* __restrict__ v_info,
    const float* __restrict__ bf1, const float* __restrict__ gf1,
    const float* __restrict__ bef1, const float* __restrict__ mf1,
    const float* __restrict__ vf1,
    const float* __restrict__ bf2, const float* __restrict__ gf2,
    const float* __restrict__ bef2, const float* __restrict__ mf2,
    const float* __restrict__ vf2,
    unsigned short* __restrict__ Bh, unsigned short* __restrict__ Bl,
    float* __restrict__ bias3,
    float4* __restrict__ w2q, float* __restrict__ bias2,
    unsigned short* __restrict__ Bedge,   // [4][64][8] bf16
    float4* __restrict__ qTab4,
    float* __restrict__ sf1, float* __restrict__ cf1,
    float* __restrict__ sf2, float* __restrict__ cf2)
{
    const int blk = blockIdx.x, tid = threadIdx.x;
    if (blk < 64) {
        const int t = blk * 256 + tid;        // (kt,nt,lane)
        const int kt = t >> 12;
        const int nt = (t >> 6) & 63;
        const int lane = t & 63;
        const int o  = nt * 16 + (lane & 15);
        const int kb = kt * 32 + ((lane >> 4) << 3);
        const float a3 = g3[o] * rsqrtf(v3[o] + EPS);
        unsigned short hi[8], lo[8];
        #pragma unroll
        for (int j = 0; j < 8; ++j) {
            const float wv = a3 * w3[(size_t)o * 128 + kb + j];
            hi[j] = bf16r(wv);
            lo[j] = bf16r(wv - bf2f(hi[j]));
        }
        #pragma unroll
        for (int j = 0; j < 8; ++j) {
            Bh[(size_t)t * 8 + j] = hi[j];
            Bl[(size_t)t * 8 + j] = lo[j];
        }
    } else if (blk == 64) {
        for (int idx = tid; idx < 2048; idx += 256) {
            const int o2 = idx & 127, cq = idx >> 7;
            const float a2 = g2[o2] * rsqrtf(v2[o2] + EPS);
            const float4 w = *(const float4*)(w2 + (size_t)o2 * 64 + cq * 4);
            w2q[cq * 128 + o2] = make_float4(a2 * w.x, a2 * w.y, a2 * w.z, a2 * w.w);
        }
        if (tid < 128) {
            const float a2 = g2[tid] * rsqrtf(v2[tid] + EPS);
            bias2[tid] = a2 * (b2[tid] - m2[tid]) + be2[tid];
        }
    } else {
        // Bedge: edge-conv B-frag.  K-slot pairing (with A):
        //   k0-2: dh.ch   k3-5: dh.cl   k6-8: dl.ch   rest 0
        // B slots grp0: [ch0,ch1,ch2,cl0,cl1,cl2,ch0,ch1]; grp1: [ch2,0,...]
        {
            const int nt = tid >> 6, lane = tid & 63;
            const int grp = lane >> 4;
            const int o = nt * 16 + (lane & 15);
            const float a = g_info[o] * rsqrtf(v_info[o] + EPS);
            const float c0 = a * w_info[o*6+0];
            const float c1 = a * w_info[o*6+1];
            const float c2 = a * w_info[o*6+2];
            const unsigned short ch0 = bf16r(c0), ch1 = bf16r(c1), ch2 = bf16r(c2);
            const unsigned short cl0 = bf16r(c0 - bf2f(ch0));
            const unsigned short cl1 = bf16r(c1 - bf2f(ch1));
            const unsigned short cl2 = bf16r(c2 - bf2f(ch2));
            unsigned short out[8] = {0,0,0,0,0,0,0,0};
            if (grp == 0) {
                out[0]=ch0; out[1]=ch1; out[2]=ch2;
                out[3]=cl0; out[4]=cl1; out[5]=cl2;
                out[6]=ch0; out[7]=ch1;
            } else if (grp == 1) {
                out[0]=ch2;
            }
            #pragma unroll
            for (int j = 0; j < 8; ++j)
                Bedge[(size_t)(nt*64 + lane)*8 + j] = out[j];
        }
        if (tid < 64) {
            const int o = tid;
            const float w0 = w_info[o*6+0], w1 = w_info[o*6+1], w2c = w_info[o*6+2];
            const float w3c = w_info[o*6+3], w4 = w_info[o*6+4], w5 = w_info[o*6+5];
            const float a = g_info[o] * rsqrtf(v_info[o] + EPS);
            qTab4[o] = make_float4(a*(w3c-w0), a*(w4-w1), a*(w5-w2c),
                                   a*(b_info[o]-m_info[o]) + be_info[o]);
        }
        for (int c = tid; c < 1024; c += 256) {
            const float a3 = g3[c] * rsqrtf(v3[c] + EPS);
            bias3[c] = a3 * (b3[c] - m3[c]) + be3[c];
        }
        for (int c = tid; c < 512; c += 256) {
            const float s = gf1[c] * rsqrtf(vf1[c] + EPS);
            sf1[c] = s;
            cf1[c] = s * (bf1[c] - mf1[c]) + bef1[c];
        }
        {
            const int c = tid;
            const float s = gf2[c] * rsqrtf(vf2[c] + EPS);
            sf2[c] = s;
            cf2[c] = s * (bf2[c] - mf2[c]) + bef2[c];
        }
    }
}

// ---------------------------------------------------------------------------
// k_edgemm: edge-conv (6->64) + BN + ReLU + max over K=520 via MFMA, fused
// with conv2 (64->128) + BN + ReLU + bf16 hi/lo split for conv3.
// R14 lesson: five VALU/LDS formulations all plateau 40-52us at ~7x the pipe
// floor -> switch engine.  Per (b,n): C[520x64] = D[520x3] x Cw[3x64] is an
// MFMA GEMM (K=3 padded in K=32; bf16x3 triple product packed into ONE MFMA
// via K-slots 0-8).  Column-max via in-register fmax on the C-frag + 2
// shfl_xor.  No part[], no DPP rounds, no sched_barriers.
// 256 blocks (1/b), 512 thr (8 waves; escapes the 1024-thr 64-VGPR cap).
// Wave w handles n = w, w+8.  Pad rows 520..527 clamped to row 519
// (duplicates can't exceed the true max - maskless).
// ---------------------------------------------------------------------------
__global__ __launch_bounds__(512) void k_edgemm(
    const float* __restrict__ pts,        // [256,15,3]
    const float* __restrict__ info,       // [256,520,15,3]
    const unsigned short* __restrict__ Bedge,  // [4][64][8]
    const float4* __restrict__ qTab4,     // [64]
    const float4* __restrict__ w2q,       // [16][128]
    const float* __restrict__ bias2,      // [128]
    unsigned short* __restrict__ h2h,     // [256][16][128] bf16 hi
    unsigned short* __restrict__ h2l)     // [256][16][128] bf16 lo
{
    __shared__ float ds[23400];           // 93600 B  [k][n][3]
    __shared__ float h1s[960];            // 3840 B   [15][64]

    const int tid = threadIdx.x;
    const int b = blockIdx.x;

    { // coalesced staging of the full 520 k-rows for this b
        const float4* src = (const float4*)(info + (size_t)b * 23400);
        float4* dst = (float4*)ds;
        for (int i = tid; i < 5850; i += 512) dst[i] = src[i];
    }
    __syncthreads();

    const int wave = tid >> 6, lane = tid & 63;
    const int lrow = lane & 15;

    // B-frags for the 4 o-tiles (16B/lane coalesced, hoisted)
    short8v bfrag[4];
    #pragma unroll
    for (int nt = 0; nt < 4; ++nt)
        bfrag[nt] = *(const short8v*)(Bedge + (size_t)(nt*64 + lane)*8);

    const f32x4 zero4 = {0.f, 0.f, 0.f, 0.f};

    for (int n = wave; n < 15; n += 8) {
        f32x4 cm0 = {-INFINITY,-INFINITY,-INFINITY,-INFINITY};
        f32x4 cm1 = cm0, cm2 = cm0, cm3 = cm0;

        for (int mt = 0; mt < 33; ++mt) {
            int row = mt*16 + lrow;
            row = row > 519 ? 519 : row;
            const float* p = ds + row*45 + n*3;
            short8v afrag = {0,0,0,0,0,0,0,0};
            if (lane < 16) {
                const float d0 = p[0], d1 = p[1], d2 = p[2];
                const unsigned short h0 = bf16r(d0), h1 = bf16r(d1), h2v = bf16r(d2);
                const unsigned short l0 = bf16r(d0 - bf2f(h0));
                const unsigned short l1 = bf16r(d1 - bf2f(h1));
                afrag[0]=(short)h0; afrag[1]=(short)h1; afrag[2]=(short)h2v;
                afrag[3]=(short)h0; afrag[4]=(short)h1; afrag[5]=(short)h2v;
                afrag[6]=(short)l0; afrag[7]=(short)l1;
            } else if (lane < 32) {
                const float d2 = p[2];
                const unsigned short h2v = bf16r(d2);
                afrag[0] = (short)bf16r(d2 - bf2f(h2v));
            }
            f32x4 r0 = __builtin_amdgcn_mfma_f32_16x16x32_bf16(afrag, bfrag[0], zero4, 0,0,0);
            f32x4 r1 = __builtin_amdgcn_mfma_f32_16x16x32_bf16(afrag, bfrag[1], zero4, 0,0,0);
            f32x4 r2 = __builtin_amdgcn_mfma_f32_16x16x32_bf16(afrag, bfrag[2], zero4, 0,0,0);
            f32x4 r3 = __builtin_amdgcn_mfma_f32_16x16x32_bf16(afrag, bfrag[3], zero4, 0,0,0);
            #pragma unroll
            for (int c = 0; c < 4; ++c) {
                cm0[c] = fmaxf(cm0[c], r0[c]);
                cm1[c] = fmaxf(cm1[c], r1[c]);
                cm2[c] = fmaxf(cm2[c], r2[c]);
                cm3[c] = fmaxf(cm3[c], r3[c]);
            }
        }

        // epilogue: fold 4 rows/lane, then cross-lane over row-groups
        const float x0 = pts[b*45 + n*3 + 0];
        const float x1 = pts[b*45 + n*3 + 1];
        const float x2 = pts[b*45 + n*3 + 2];
        #pragma unroll
        for (int nt = 0; nt < 4; ++nt) {
            f32x4 cm = (nt==0) ? cm0 : (nt==1) ? cm1 : (nt==2) ? cm2 : cm3;
            float m = fmaxf(fmaxf(cm[0], cm[1]), fmaxf(cm[2], cm[3]));
            m = fmaxf(m, __shfl_xor(m, 16));
            m = fmaxf(m, __shfl_xor(m, 32));
            if (lane < 16) {
                const int o = nt*16 + lane;
                const float4 qv = qTab4[o];
                const float bias = fmaf(qv.x, x0, fmaf(qv.y, x1,
                                   fmaf(qv.z, x2, qv.w)));
                h1s[n*64 + o] = fmaxf(m + bias, 0.f);
            }
        }
    }
    __syncthreads();

    // conv2: 16x128 outputs (row 15 = pad 0), bf16 hi/lo split write
    for (int idx = tid; idx < 2048; idx += 512) {
        const int o2 = idx & 127, n = idx >> 7;   // n: 0..15
        float val = 0.f;
        if (n < 15) {
            float acc = 0.f;
            #pragma unroll
            for (int cq = 0; cq < 16; ++cq) {
                const float4 h4 = *(const float4*)(&h1s[n*64 + cq*4]);
                const float4 w4 = w2q[cq*128 + o2];
                acc = fmaf(w4.x, h4.x, fmaf(w4.y, h4.y,
                      fmaf(w4.z, h4.z, fmaf(w4.w, h4.w, acc))));
            }
            val = fmaxf(acc + bias2[o2], 0.f);
        }
        const unsigned short hi = bf16r(val);
        const unsigned short lo = bf16r(val - bf2f(hi));
        h2h[(size_t)b*2048 + n*128 + o2] = hi;
        h2l[(size_t)b*2048 + n*128 + o2] = lo;
    }
}

// ---------------------------------------------------------------------------
// k_s3: conv3 via bf16x3-split MFMA + global max over N=15.  (validated R9)
// ---------------------------------------------------------------------------
__global__ __launch_bounds__(256) void k_s3(
    const unsigned short* __restrict__ h2h,
    const unsigned short* __restrict__ h2l,
    const unsigned short* __restrict__ Bh,
    const unsigned short* __restrict__ Bl,
    const float* __restrict__ bias3,
    float* __restrict__ gout)         // [256,1024]
{
    const int tid = threadIdx.x;
    const int b = blockIdx.x;
    const int wave = tid >> 6, lane = tid & 63;
    const int arow = lane & 15, agrp = lane >> 4;

    short8v ahi[4], alo[4];
    {
        const unsigned short* Ab = h2h + (size_t)b*2048 + arow*128 + agrp*8;
        const unsigned short* Al = h2l + (size_t)b*2048 + arow*128 + agrp*8;
        #pragma unroll
        for (int kt = 0; kt < 4; ++kt) {
            ahi[kt] = *(const short8v*)(Ab + kt*32);
            alo[kt] = *(const short8v*)(Al + kt*32);
        }
    }

    for (int ntl = 0; ntl < 16; ++ntl) {
        const int nt = wave * 16 + ntl;
        f32x4 a0 = {0.f, 0.f, 0.f, 0.f};
        f32x4 a1 = a0, a2 = a0;
        #pragma unroll
        for (int kt = 0; kt < 4; ++kt) {
            const size_t off = (((size_t)kt*64 + nt)*64 + lane) * 8;
            const short8v bh = *(const short8v*)(Bh + off);
            const short8v bl = *(const short8v*)(Bl + off);
            a0 = __builtin_amdgcn_mfma_f32_16x16x32_bf16(ahi[kt], bh, a0, 0, 0, 0);
            a1 = __builtin_amdgcn_mfma_f32_16x16x32_bf16(ahi[kt], bl, a1, 0, 0, 0);
            a2 = __builtin_amdgcn_mfma_f32_16x16x32_bf16(alo[kt], bh, a2, 0, 0, 0);
        }
        const float r0 = a0[0] + a1[0] + a2[0];
        const float r1 = a0[1] + a1[1] + a2[1];
        const float r2 = a0[2] + a1[2] + a2[2];
        const float r3 = a0[3] + a1[3] + a2[3];
        float m = fmaxf(fmaxf(r0, r1), r2);
        if (agrp != 3) m = fmaxf(m, r3);          // exclude pad row 15
        m = fmaxf(m, __shfl_xor(m, 16));
        m = fmaxf(m, __shfl_xor(m, 32));
        if (lane < 16)
            gout[(size_t)b*1024 + nt*16 + lane] = m + bias3[nt*16 + lane];
    }
}

// ---------------------------------------------------------------------------
// k_fc1p: fc1 split-K=2 raw partials.  grid (8,16,2), 32x32 tile.
// ---------------------------------------------------------------------------
__global__ __launch_bounds__(256) void k_fc1p(
    const float* __restrict__ A,      // g [256][1024]
    const float* __restrict__ W,      // wf1 [512][1024]
    float* __restrict__ P)            // [2][256][512]
{
    __shared__ float As[32][36];
    __shared__ float Ws[32][36];

    const int tid = threadIdx.x;
    const int bm = blockIdx.x * 32, bn = blockIdx.y * 32;
    const int ks = blockIdx.z;
    const int ml = (tid >> 4) * 2, nl = (tid & 15) * 2;
    const int row = tid >> 3, kq = (tid & 7) * 4;

    float acc00 = 0.f, acc01 = 0.f, acc10 = 0.f, acc11 = 0.f;

    for (int k0 = 0; k0 < 512; k0 += 32) {
        const int ch = ks * 512 + k0 + kq;
        const float4 av = *(const float4*)(A + (size_t)(bm + row) * 1024 + ch);
        const float4 wv = *(const float4*)(W + (size_t)(bn + row) * 1024 + ch);
        __syncthreads();
        *(float4*)(&As[row][kq]) = av;
        *(float4*)(&Ws[row][kq]) = wv;
        __syncthreads();
        const float4* a0p = (const float4*)(&As[ml][0]);
        const float4* a1p = (const float4*)(&As[ml + 1][0]);
        const float4* b0p = (const float4*)(&Ws[nl][0]);
        const float4* b1p = (const float4*)(&Ws[nl + 1][0]);
        #pragma unroll
        for (int q = 0; q < 8; ++q) {
            const float4 a0 = a0p[q], a1 = a1p[q], b0 = b0p[q], b1 = b1p[q];
            acc00 = fmaf(a0.x, b0.x, fmaf(a0.y, b0.y, fmaf(a0.z, b0.z, fmaf(a0.w, b0.w, acc00))));
            acc01 = fmaf(a0.x, b1.x, fmaf(a0.y, b1.y, fmaf(a0.z, b1.z, fmaf(a0.w, b1.w, acc01))));
            acc10 = fmaf(a1.x, b0.x, fmaf(a1.y, b0.y, fmaf(a1.z, b0.z, fmaf(a1.w, b0.w, acc10))));
            acc11 = fmaf(a1.x, b1.x, fmaf(a1.y, b1.y, fmaf(a1.z, b1.z, fmaf(a1.w, b1.w, acc11))));
        }
    }
    float* p0 = P + (size_t)ks * 131072 + (size_t)(bm + ml) * 512 + bn + nl;
    p0[0] = acc00; p0[1] = acc01;
    float* p1 = p0 + 512;
    p1[0] = acc10; p1[1] = acc11;
}

// ---------------------------------------------------------------------------
// k_fc2p: fc2 split-K=2; A-tile finishes f1 (BN+ReLU+combine) on the fly.
// ---------------------------------------------------------------------------
__global__ __launch_bounds__(256) void k_fc2p(
    const float* __restrict__ fp,     // [2][256][512]
    const float* __restrict__ sf1, const float* __restrict__ cf1,
    const float* __restrict__ W,      // wf2 [256][512]
    float* __restrict__ P2)           // [2][256][256]
{
    __shared__ float As[32][36];
    __shared__ float Ws[32][36];

    const int tid = threadIdx.x;
    const int bm = blockIdx.x * 32, bn = blockIdx.y * 32;
    const int ks = blockIdx.z;
    const int ml = (tid >> 4) * 2, nl = (tid & 15) * 2;
    const int row = tid >> 3, kq = (tid & 7) * 4;

    float acc00 = 0.f, acc01 = 0.f, acc10 = 0.f, acc11 = 0.f;

    for (int k0 = 0; k0 < 256; k0 += 32) {
        const int ch = ks * 256 + k0 + kq;
        const float4 p0 = *(const float4*)(fp + (size_t)(bm + row) * 512 + ch);
        const float4 p1 = *(const float4*)(fp + 131072 + (size_t)(bm + row) * 512 + ch);
        const float4 s4 = *(const float4*)(sf1 + ch);
        const float4 c4 = *(const float4*)(cf1 + ch);
        float4 av;
        av.x = fmaxf(fmaf(s4.x, p0.x + p1.x, c4.x), 0.f);
        av.y = fmaxf(fmaf(s4.y, p0.y + p1.y, c4.y), 0.f);
        av.z = fmaxf(fmaf(s4.z, p0.z + p1.z, c4.z), 0.f);
        av.w = fmaxf(fmaf(s4.w, p0.w + p1.w, c4.w), 0.f);
        const float4 wv = *(const float4*)(W + (size_t)(bn + row) * 512 + ch);
        __syncthreads();
        *(float4*)(&As[row][kq]) = av;
        *(float4*)(&Ws[row][kq]) = wv;
        __syncthreads();
        const float4* a0p = (const float4*)(&As[ml][0]);
        const float4* a1p = (const float4*)(&As[ml + 1][0]);
        const float4* b0p = (const float4*)(&Ws[nl][0]);
        const float4* b1p = (const float4*)(&Ws[nl + 1][0]);
        #pragma unroll
        for (int q = 0; q < 8; ++q) {
            const float4 a0 = a0p[q], a1 = a1p[q], b0 = b0p[q], b1 = b1p[q];
            acc00 = fmaf(a0.x, b0.x, fmaf(a0.y, b0.y, fmaf(a0.z, b0.z, fmaf(a0.w, b0.w, acc00))));
            acc01 = fmaf(a0.x, b1.x, fmaf(a0.y, b1.y, fmaf(a0.z, b1.z, fmaf(a0.w, b1.w, acc01))));
            acc10 = fmaf(a1.x, b0.x, fmaf(a1.y, b0.y, fmaf(a1.z, b0.z, fmaf(a1.w, b0.w, acc10))));
            acc11 = fmaf(a1.x, b1.x, fmaf(a1.y, b1.y, fmaf(a1.z, b1.z, fmaf(a1.w, b1.w, acc11))));
        }
    }
    float* q0 = P2 + (size_t)ks * 65536 + (size_t)(bm + ml) * 256 + bn + nl;
    q0[0] = acc00; q0[1] = acc01;
    float* q1 = q0 + 256;
    q1[0] = acc10; q1[1] = acc11;
}

// ---------------------------------------------------------------------------
// k_ep2: f2 = relu(sf2*(P2[0]+P2[1]) + cf2)
// ---------------------------------------------------------------------------
__global__ __launch_bounds__(256) void k_ep2(
    const float* __restrict__ P2, const float* __restrict__ sf2,
    const float* __restrict__ cf2, float* __restrict__ f2)
{
    const int i = blockIdx.x * 256 + threadIdx.x;
    const int n = i & 255;
    const float v = P2[i] + P2[65536 + i];
    f2[i] = fmaxf(fmaf(sf2[n], v, cf2[n]), 0.f);
}

// ---------------------------------------------------------------------------
// k_fc3: C = A*W^T + bias
// ---------------------------------------------------------------------------
__global__ __launch_bounds__(256) void k_fc3(
    const float* __restrict__ A, const float* __restrict__ W,
    const float* __restrict__ bias, float* __restrict__ C, int K, int Nc)
{
    __shared__ float As[32][36];
    __shared__ float Ws[32][36];

    const int tid = threadIdx.x;
    const int bm = blockIdx.x * 32, bn = blockIdx.y * 32;
    const int ml = (tid >> 4) * 2, nl = (tid & 15) * 2;
    const int row = tid >> 3, kq = (tid & 7) * 4;

    float acc00 = 0.f, acc01 = 0.f, acc10 = 0.f, acc11 = 0.f;

    for (int k0 = 0; k0 < K; k0 += 32) {
        const float4 av = *(const float4*)(A + (size_t)(bm + row) * K + k0 + kq);
        const float4 wv = *(const float4*)(W + (size_t)(bn + row) * K + k0 + kq);
        __syncthreads();
        *(float4*)(&As[row][kq]) = av;
        *(float4*)(&Ws[row][kq]) = wv;
        __syncthreads();
        const float4* a0p = (const float4*)(&As[ml][0]);
        const float4* a1p = (const float4*)(&As[ml + 1][0]);
        const float4* b0p = (const float4*)(&Ws[nl][0]);
        const float4* b1p = (const float4*)(&Ws[nl + 1][0]);
        #pragma unroll
        for (int q = 0; q < 8; ++q) {
            const float4 a0 = a0p[q], a1 = a1p[q], b0 = b0p[q], b1 = b1p[q];
            acc00 = fmaf(a0.x, b0.x, fmaf(a0.y, b0.y, fmaf(a0.z, b0.z, fmaf(a0.w, b0.w, acc00))));
            acc01 = fmaf(a0.x, b1.x, fmaf(a0.y, b1.y, fmaf(a0.z, b1.z, fmaf(a0.w, b1.w, acc01))));
            acc10 = fmaf(a1.x, b0.x, fmaf(a1.y, b0.y, fmaf(a1.z, b0.z, fmaf(a1.w, b0.w, acc10))));
            acc11 = fmaf(a1.x, b1.x, fmaf(a1.y, b1.y, fmaf(a1.z, b1.z, fmaf(a1.w, b1.w, acc11))));
        }
    }

    const int n0 = bn + nl, n1 = n0 + 1;
    float* cr0 = C + (size_t)(bm + ml) * Nc + n0;
    cr0[0] = acc00 + bias[n0]; cr0[1] = acc01 + bias[n1];
    float* cr1 = C + (size_t)(bm + ml + 1) * Nc + n0;
    cr1[0] = acc10 + bias[n0]; cr1[1] = acc11 + bias[n1];
}

// ---------------------------------------------------------------------------
extern "C" void kernel_launch(void* const* d_in, const int* in_sizes, int n_in,
                              void* d_out, int out_size, void* d_ws, size_t ws_size,
                              hipStream_t stream)
{
    const float* pts     = (const float*)d_in[0];
    const float* info    = (const float*)d_in[2];
    const float* w_info  = (const float*)d_in[3];
    const float* b_info  = (const float*)d_in[4];
    const float* g_info  = (const float*)d_in[5];
    const float* be_info = (const float*)d_in[6];
    const float* m_info  = (const float*)d_in[7];
    const float* v_info  = (const float*)d_in[8];
    const float* w2      = (const float*)d_in[9];
    const float* b2      = (const float*)d_in[10];
    const float* g2      = (const float*)d_in[11];
    const float* be2     = (const float*)d_in[12];
    const float* m2      = (const float*)d_in[13];
    const float* v2      = (const float*)d_in[14];
    const float* w3      = (const float*)d_in[15];
    const float* b3      = (const float*)d_in[16];
    const float* g3      = (const float*)d_in[17];
    const float* be3     = (const float*)d_in[18];
    const float* m3      = (const float*)d_in[19];
    const float* v3      = (const float*)d_in[20];
    const float* wf1     = (const float*)d_in[21];
    const float* bf1     = (const float*)d_in[22];
    const float* gf1     = (const float*)d_in[23];
    const float* bef1    = (const float*)d_in[24];
    const float* mf1     = (const float*)d_in[25];
    const float* vf1     = (const float*)d_in[26];
    const float* wf2     = (const float*)d_in[27];
    const float* bf2     = (const float*)d_in[28];
    const float* gf2     = (const float*)d_in[29];
    const float* bef2    = (const float*)d_in[30];
    const float* mf2     = (const float*)d_in[31];
    const float* vf2     = (const float*)d_in[32];
    const float* wf3     = (const float*)d_in[33];
    const float* bf3     = (const float*)d_in[34];

    float* ws = (float*)d_ws;
    unsigned short* h2h   = (unsigned short*)(ws + 491520);      // 524288 bf16
    unsigned short* h2l   = (unsigned short*)(ws + 753664);      // 524288 bf16
    float*          g     = ws + 1015808;                        // 262144
    unsigned short* Bh    = (unsigned short*)(ws + 1277952);     // 131072 bf16
    unsigned short* Bl    = (unsigned short*)(ws + 1343488);     // 131072 bf16
    float*          bias3 = ws + 1409024;                        // 1024
    float4*         w2q   = (float4*)(ws + 1410048);             // 8192
    float*          bias2 = ws + 1418240;                        // 128
    float4*         qTab4 = (float4*)(ws + 1418624);             // 256
    float*          sf1   = ws + 1418880;                        // 512
    float*          cf1   = ws + 1419392;                        // 512
    float*          sf2   = ws + 1419904;                        // 256
    float*          cf2   = ws + 1420160;                        // 256
    unsigned short* Bedge = (unsigned short*)(ws + 1420416);     // 2048 bf16
    float*          fp    = ws;                                  // [2][256][512] (free region)
    float*          P2    = ws + 262144;                         // [2][256][256]

    float* ret = (float*)d_out;            // [256, 800]
    float* f2  = ret + 256 * 800;          // [256, 256]

    k_pre<<<66, 256, 0, stream>>>(
        w3, b3, g3, be3, m3, v3,
        w2, b2, g2, be2, m2, v2,
        w_info, b_info, g_info, be_info, m_info, v_info,
        bf1, gf1, bef1, mf1, vf1,
        bf2, gf2, bef2, mf2, vf2,
        Bh, Bl, bias3, w2q, bias2, Bedge, qTab4, sf1, cf1, sf2, cf2);

    k_edgemm<<<256, 512, 0, stream>>>(pts, info, Bedge, qTab4,
                                      w2q, bias2, h2h, h2l);

    k_s3<<<256, 256, 0, stream>>>(h2h, h2l, Bh, Bl, bias3, g);

    k_fc1p<<<dim3(8, 16, 2), 256, 0, stream>>>(g, wf1, fp);

    k_fc2p<<<dim3(8, 8, 2), 256, 0, stream>>>(fp, sf1, cf1, wf2, P2);

    k_ep2<<<256, 256, 0, stream>>>(P2, sf2, cf2, f2);

    k_fc3<<<dim3(8, 25), 256, 0, stream>>>(f2, wf3, bf3, ret, 256, 800);
}

// Round 17
// 93.768 us; speedup vs baseline: 1.2999x; 1.2035x over previous
//
#include <hip/hip_runtime.h>
#include <math.h>

#define EPS 1e-5f

typedef __attribute__((ext_vector_type(8))) short short8v;
typedef __attribute__((ext_vector_type(4))) float f32x4;
typedef __attribute__((ext_vector_type(16))) float f32x16;

// ---- bf16 split helpers (RNE) ----
__device__ __forceinline__ unsigned short bf16r(float x) {
    unsigned u = __float_as_uint(x);
    return (unsigned short)((u + 0x7FFFu + ((u >> 16) & 1u)) >> 16);
}
__device__ __forceinline__ float bf2f(unsigned short h) {
    return __uint_as_float(((unsigned)h) << 16);
}
// pack float -> dword (lo16 = bf16 hi part, hi16 = bf16 lo-correction)
__device__ __forceinline__ unsigned packhl(float x) {
    const unsigned short h = bf16r(x);
    const unsigned short l = bf16r(x - bf2f(h));
    return (unsigned)h | ((unsigned)l << 16);
}

// ---------------------------------------------------------------------------
// k_pre (66 blocks): Bpack (conv3 bf16-split B), w2q/bias2 (conv2 fold),
// Bedge32 (edge-conv 32x32 MFMA B-frags), qTab4, bias3, sf1/cf1, sf2/cf2.
// ---------------------------------------------------------------------------
__global__ __launch_bounds__(256) void k_pre(
    const float* __restrict__ w3, const float* __restrict__ b3,
    const float* __restrict__ g3, const float* __restrict__ be3,
    const float* __restrict__ m3, const float* __restrict__ v3,
    const float* __restrict__ w2, const float* __restrict__ b2,
    const float* __restrict__ g2, const float* __restrict__ be2,
    const float* __restrict__ m2, const float* __restrict__ v2,
    const float* __restrict__ w_info, const float* __restrict__ b_info,
    const float* __restrict__ g_info, const float* __restrict__ be_info,
    const float* __restrict__ m_info, const float* __restrict__ v_info,
    const float* __restrict__ bf1, const float* __restrict__ gf1,
    const float* __restrict__ bef1, const float* __restrict__ mf1,
    const float* __restrict__ vf1,
    const float* __restrict__ bf2, const float* __restrict__ gf2,
    const float* __restrict__ bef2, const float* __restrict__ mf2,
    const float* __restrict__ vf2,
    unsigned short* __restrict__ Bh, unsigned short* __restrict__ Bl,
    float* __restrict__ bias3,
    float4* __restrict__ w2q, float* __restrict__ bias2,
    unsigned short* __restrict__ Bedge,   // [2][64][8] bf16 (32x32 frags)
    float4* __restrict__ qTab4,
    float* __restrict__ sf1, float* __restrict__ cf1,
    float* __restrict__ sf2, float* __restrict__ cf2)
{
    const int blk = blockIdx.x, tid = threadIdx.x;
    if (blk < 64) {
        const int t = blk * 256 + tid;        // (kt,nt,lane)
        const int kt = t >> 12;
        const int nt = (t >> 6) & 63;
        const int lane = t & 63;
        const int o  = nt * 16 + (lane & 15);
        const int kb = kt * 32 + ((lane >> 4) << 3);
        const float a3 = g3[o] * rsqrtf(v3[o] + EPS);
        unsigned short hi[8], lo[8];
        #pragma unroll
        for (int j = 0; j < 8; ++j) {
            const float wv = a3 * w3[(size_t)o * 128 + kb + j];
            hi[j] = bf16r(wv);
            lo[j] = bf16r(wv - bf2f(hi[j]));
        }
        #pragma unroll
        for (int j = 0; j < 8; ++j) {
            Bh[(size_t)t * 8 + j] = hi[j];
            Bl[(size_t)t * 8 + j] = lo[j];
        }
    } else if (blk == 64) {
        for (int idx = tid; idx < 2048; idx += 256) {
            const int o2 = idx & 127, cq = idx >> 7;
            const float a2 = g2[o2] * rsqrtf(v2[o2] + EPS);
            const float4 w = *(const float4*)(w2 + (size_t)o2 * 64 + cq * 4);
            w2q[cq * 128 + o2] = make_float4(a2 * w.x, a2 * w.y, a2 * w.z, a2 * w.w);
        }
        if (tid < 128) {
            const float a2 = g2[tid] * rsqrtf(v2[tid] + EPS);
            bias2[tid] = a2 * (b2[tid] - m2[tid]) + be2[tid];
        }
    } else {
        // Bedge32: 32x32 MFMA B-frag.  A K-slots: k0-2=dh, k3-5=dh, k6-7=dl01,
        // k8=dl2.  B lanes 0-31 (k0-7): [ch0,ch1,ch2,cl0,cl1,cl2,ch0,ch1];
        // lanes 32-63 (k8-15): [ch2,0,...].  o = nt*32 + (lane&31).
        if (tid < 128) {
            const int nt = tid >> 6, lane = tid & 63;
            const int grp = lane >> 5;
            const int o = nt * 32 + (lane & 31);
            const float a = g_info[o] * rsqrtf(v_info[o] + EPS);
            const float c0 = a * w_info[o*6+0];
            const float c1 = a * w_info[o*6+1];
            const float c2 = a * w_info[o*6+2];
            const unsigned short ch0 = bf16r(c0), ch1 = bf16r(c1), ch2 = bf16r(c2);
            const unsigned short cl0 = bf16r(c0 - bf2f(ch0));
            const unsigned short cl1 = bf16r(c1 - bf2f(ch1));
            const unsigned short cl2 = bf16r(c2 - bf2f(ch2));
            unsigned short out[8] = {0,0,0,0,0,0,0,0};
            if (grp == 0) {
                out[0]=ch0; out[1]=ch1; out[2]=ch2;
                out[3]=cl0; out[4]=cl1; out[5]=cl2;
                out[6]=ch0; out[7]=ch1;
            } else {
                out[0]=ch2;
            }
            #pragma unroll
            for (int j = 0; j < 8; ++j)
                Bedge[(size_t)(nt*64 + lane)*8 + j] = out[j];
        }
        if (tid < 64) {
            const int o = tid;
            const float w0 = w_info[o*6+0], w1 = w_info[o*6+1], w2c = w_info[o*6+2];
            const float w3c = w_info[o*6+3], w4 = w_info[o*6+4], w5 = w_info[o*6+5];
            const float a = g_info[o] * rsqrtf(v_info[o] + EPS);
            qTab4[o] = make_float4(a*(w3c-w0), a*(w4-w1), a*(w5-w2c),
                                   a*(b_info[o]-m_info[o]) + be_info[o]);
        }
        for (int c = tid; c < 1024; c += 256) {
            const float a3 = g3[c] * rsqrtf(v3[c] + EPS);
            bias3[c] = a3 * (b3[c] - m3[c]) + be3[c];
        }
        for (int c = tid; c < 512; c += 256) {
            const float s = gf1[c] * rsqrtf(vf1[c] + EPS);
            sf1[c] = s;
            cf1[c] = s * (bf1[c] - mf1[c]) + bef1[c];
        }
        {
            const int c = tid;
            const float s = gf2[c] * rsqrtf(vf2[c] + EPS);
            sf2[c] = s;
            cf2[c] = s * (bf2[c] - mf2[c]) + bef2[c];
        }
    }
}

// ---------------------------------------------------------------------------
// k_edgemm32: edge-conv + BN + ReLU + max over K=520 via 32x32x16 MFMA,
// fused with conv2 + bf16 split.
// R16 lesson: per-mt bf16 conversion VALU (16 useful lanes) was the kernel.
// Fix: (1) convert at STAGING - dsb[k][n][c] is one packed dword (bf16
// hi|lo) per source float, so per-mt prep = 3 ds_read_b32 + 4 bit-merges;
// (2) 32x32x16 MFMA: 17 mt x 2 MFMA (vs 33x4), all 64 lanes carry A.
// C-frag: col=lane&31, row=(reg&3)+8(reg>>2)+4(lane>>5); column max =
// per-lane fmax over 16 regs + shfl_xor(32).  Rows >519 clamped (max-safe).
// ---------------------------------------------------------------------------
__global__ __launch_bounds__(512) void k_edgemm32(
    const float* __restrict__ pts,        // [256,15,3]
    const float* __restrict__ info,       // [256,520,15,3]
    const unsigned short* __restrict__ Bedge,  // [2][64][8]
    const float4* __restrict__ qTab4,     // [64]
    const float4* __restrict__ w2q,       // [16][128]
    const float* __restrict__ bias2,      // [128]
    unsigned short* __restrict__ h2h,     // [256][16][128] bf16 hi
    unsigned short* __restrict__ h2l)     // [256][16][128] bf16 lo
{
    __shared__ unsigned dsb[23400];       // 93600 B  [k][n][c] packed hi|lo
    __shared__ float h1s[960];            // 3840 B   [15][64]

    const int tid = threadIdx.x;
    const int b = blockIdx.x;

    { // coalesced staging + bf16 hi/lo packing (conversion amortized here)
        const float4* src = (const float4*)(info + (size_t)b * 23400);
        uint4* dst = (uint4*)dsb;
        for (int i = tid; i < 5850; i += 512) {
            const float4 v = src[i];
            uint4 pv;
            pv.x = packhl(v.x); pv.y = packhl(v.y);
            pv.z = packhl(v.z); pv.w = packhl(v.w);
            dst[i] = pv;
        }
    }
    __syncthreads();

    const int wave = tid >> 6, lane = tid & 63;
    const int la = lane & 31;
    const bool hiHalf = lane >= 32;

    // B-frags for the 2 o-tiles (16B/lane coalesced, hoisted)
    short8v bfrag0 = *(const short8v*)(Bedge + (size_t)(0*64 + lane)*8);
    short8v bfrag1 = *(const short8v*)(Bedge + (size_t)(1*64 + lane)*8);

    const f32x16 zero16 = {0.f,0.f,0.f,0.f,0.f,0.f,0.f,0.f,
                           0.f,0.f,0.f,0.f,0.f,0.f,0.f,0.f};

    for (int n = wave; n < 15; n += 8) {
        float m0 = -INFINITY, m1 = -INFINITY;   // per-lane column maxima

        #pragma unroll 1
        for (int mt = 0; mt < 17; ++mt) {
            int row = mt*32 + la;
            row = row > 519 ? 519 : row;
            const unsigned* p = dsb + row*45 + n*3;
            int4 ai;
            if (!hiHalf) {
                const unsigned w0 = p[0], w1 = p[1], w2 = p[2];
                ai.x = (int)((w0 & 0xFFFFu) | (w1 << 16));        // dh0,dh1
                ai.y = (int)((w2 & 0xFFFFu) | (w0 << 16));        // dh2,dh0
                ai.z = (int)((w1 & 0xFFFFu) | (w2 << 16));        // dh1,dh2
                ai.w = (int)((w0 >> 16) | (w1 & 0xFFFF0000u));    // dl0,dl1
            } else {
                const unsigned w2 = p[2];
                ai.x = (int)(w2 >> 16);                           // dl2
                ai.y = 0; ai.z = 0; ai.w = 0;
            }
            const short8v afrag = *(short8v*)&ai;
            const f32x16 r0 = __builtin_amdgcn_mfma_f32_32x32x16_bf16(afrag, bfrag0, zero16, 0,0,0);
            const f32x16 r1 = __builtin_amdgcn_mfma_f32_32x32x16_bf16(afrag, bfrag1, zero16, 0,0,0);
            #pragma unroll
            for (int c = 0; c < 16; ++c) {
                m0 = fmaxf(m0, r0[c]);
                m1 = fmaxf(m1, r1[c]);
            }
        }
        // fold lane halves (complementary rows, same column)
        m0 = fmaxf(m0, __shfl_xor(m0, 32));
        m1 = fmaxf(m1, __shfl_xor(m1, 32));

        if (lane < 32) {
            const float x0 = pts[b*45 + n*3 + 0];
            const float x1 = pts[b*45 + n*3 + 1];
            const float x2 = pts[b*45 + n*3 + 2];
            {
                const int o = lane;                 // frag0: o = 0..31
                const float4 qv = qTab4[o];
                const float bias = fmaf(qv.x, x0, fmaf(qv.y, x1, fmaf(qv.z, x2, qv.w)));
                h1s[n*64 + o] = fmaxf(m0 + bias, 0.f);
            }
            {
                const int o = 32 + lane;            // frag1: o = 32..63
                const float4 qv = qTab4[o];
                const float bias = fmaf(qv.x, x0, fmaf(qv.y, x1, fmaf(qv.z, x2, qv.w)));
                h1s[n*64 + o] = fmaxf(m1 + bias, 0.f);
            }
        }
    }
    __syncthreads();

    // conv2: 16x128 outputs (row 15 = pad 0), bf16 hi/lo split write
    for (int idx = tid; idx < 2048; idx += 512) {
        const int o2 = idx & 127, n = idx >> 7;   // n: 0..15
        float val = 0.f;
        if (n < 15) {
            float acc = 0.f;
            #pragma unroll
            for (int cq = 0; cq < 16; ++cq) {
                const float4 h4 = *(const float4*)(&h1s[n*64 + cq*4]);
                const float4 w4 = w2q[cq*128 + o2];
                acc = fmaf(w4.x, h4.x, fmaf(w4.y, h4.y,
                      fmaf(w4.z, h4.z, fmaf(w4.w, h4.w, acc))));
            }
            val = fmaxf(acc + bias2[o2], 0.f);
        }
        const unsigned short hi = bf16r(val);
        const unsigned short lo = bf16r(val - bf2f(hi));
        h2h[(size_t)b*2048 + n*128 + o2] = hi;
        h2l[(size_t)b*2048 + n*128 + o2] = lo;
    }
}

// ---------------------------------------------------------------------------
// k_s3: conv3 via bf16x3-split MFMA + global max over N=15.  (validated R9)
// ---------------------------------------------------------------------------
__global__ __launch_bounds__(256) void k_s3(
    const unsigned short* __restrict__ h2h,
    const unsigned short* __restrict__ h2l,
    const unsigned short* __restrict__ Bh,
    const unsigned short* __restrict__ Bl,
    const float* __restrict__ bias3,
    float* __restrict__ gout)         // [256,1024]
{
    const int tid = threadIdx.x;
    const int b = blockIdx.x;
    const int wave = tid >> 6, lane = tid & 63;
    const int arow = lane & 15, agrp = lane >> 4;

    short8v ahi[4], alo[4];
    {
        const unsigned short* Ab = h2h + (size_t)b*2048 + arow*128 + agrp*8;
        const unsigned short* Al = h2l + (size_t)b*2048 + arow*128 + agrp*8;
        #pragma unroll
        for (int kt = 0; kt < 4; ++kt) {
            ahi[kt] = *(const short8v*)(Ab + kt*32);
            alo[kt] = *(const short8v*)(Al + kt*32);
        }
    }

    for (int ntl = 0; ntl < 16; ++ntl) {
        const int nt = wave * 16 + ntl;
        f32x4 a0 = {0.f, 0.f, 0.f, 0.f};
        f32x4 a1 = a0, a2 = a0;
        #pragma unroll
        for (int kt = 0; kt < 4; ++kt) {
            const size_t off = (((size_t)kt*64 + nt)*64 + lane) * 8;
            const short8v bh = *(const short8v*)(Bh + off);
            const short8v bl = *(const short8v*)(Bl + off);
            a0 = __builtin_amdgcn_mfma_f32_16x16x32_bf16(ahi[kt], bh, a0, 0, 0, 0);
            a1 = __builtin_amdgcn_mfma_f32_16x16x32_bf16(ahi[kt], bl, a1, 0, 0, 0);
            a2 = __builtin_amdgcn_mfma_f32_16x16x32_bf16(alo[kt], bh, a2, 0, 0, 0);
        }
        const float r0 = a0[0] + a1[0] + a2[0];
        const float r1 = a0[1] + a1[1] + a2[1];
        const float r2 = a0[2] + a1[2] + a2[2];
        const float r3 = a0[3] + a1[3] + a2[3];
        float m = fmaxf(fmaxf(r0, r1), r2);
        if (agrp != 3) m = fmaxf(m, r3);          // exclude pad row 15
        m = fmaxf(m, __shfl_xor(m, 16));
        m = fmaxf(m, __shfl_xor(m, 32));
        if (lane < 16)
            gout[(size_t)b*1024 + nt*16 + lane] = m + bias3[nt*16 + lane];
    }
}

// ---------------------------------------------------------------------------
// k_fc1p: fc1 split-K=2 raw partials.  grid (8,16,2), 32x32 tile.
// ---------------------------------------------------------------------------
__global__ __launch_bounds__(256) void k_fc1p(
    const float* __restrict__ A,      // g [256][1024]
    const float* __restrict__ W,      // wf1 [512][1024]
    float* __restrict__ P)            // [2][256][512]
{
    __shared__ float As[32][36];
    __shared__ float Ws[32][36];

    const int tid = threadIdx.x;
    const int bm = blockIdx.x * 32, bn = blockIdx.y * 32;
    const int ks = blockIdx.z;
    const int ml = (tid >> 4) * 2, nl = (tid & 15) * 2;
    const int row = tid >> 3, kq = (tid & 7) * 4;

    float acc00 = 0.f, acc01 = 0.f, acc10 = 0.f, acc11 = 0.f;

    for (int k0 = 0; k0 < 512; k0 += 32) {
        const int ch = ks * 512 + k0 + kq;
        const float4 av = *(const float4*)(A + (size_t)(bm + row) * 1024 + ch);
        const float4 wv = *(const float4*)(W + (size_t)(bn + row) * 1024 + ch);
        __syncthreads();
        *(float4*)(&As[row][kq]) = av;
        *(float4*)(&Ws[row][kq]) = wv;
        __syncthreads();
        const float4* a0p = (const float4*)(&As[ml][0]);
        const float4* a1p = (const float4*)(&As[ml + 1][0]);
        const float4* b0p = (const float4*)(&Ws[nl][0]);
        const float4* b1p = (const float4*)(&Ws[nl + 1][0]);
        #pragma unroll
        for (int q = 0; q < 8; ++q) {
            const float4 a0 = a0p[q], a1 = a1p[q], b0 = b0p[q], b1 = b1p[q];
            acc00 = fmaf(a0.x, b0.x, fmaf(a0.y, b0.y, fmaf(a0.z, b0.z, fmaf(a0.w, b0.w, acc00))));
            acc01 = fmaf(a0.x, b1.x, fmaf(a0.y, b1.y, fmaf(a0.z, b1.z, fmaf(a0.w, b1.w, acc01))));
            acc10 = fmaf(a1.x, b0.x, fmaf(a1.y, b0.y, fmaf(a1.z, b0.z, fmaf(a1.w, b0.w, acc10))));
            acc11 = fmaf(a1.x, b1.x, fmaf(a1.y, b1.y, fmaf(a1.z, b1.z, fmaf(a1.w, b1.w, acc11))));
        }
    }
    float* p0 = P + (size_t)ks * 131072 + (size_t)(bm + ml) * 512 + bn + nl;
    p0[0] = acc00; p0[1] = acc01;
    float* p1 = p0 + 512;
    p1[0] = acc10; p1[1] = acc11;
}

// ---------------------------------------------------------------------------
// k_fc2p: fc2 split-K=2; A-tile finishes f1 (BN+ReLU+combine) on the fly.
// ---------------------------------------------------------------------------
__global__ __launch_bounds__(256) void k_fc2p(
    const float* __restrict__ fp,     // [2][256][512]
    const float* __restrict__ sf1, const float* __restrict__ cf1,
    const float* __restrict__ W,      // wf2 [256][512]
    float* __restrict__ P2)           // [2][256][256]
{
    __shared__ float As[32][36];
    __shared__ float Ws[32][36];

    const int tid = threadIdx.x;
    const int bm = blockIdx.x * 32, bn = blockIdx.y * 32;
    const int ks = blockIdx.z;
    const int ml = (tid >> 4) * 2, nl = (tid & 15) * 2;
    const int row = tid >> 3, kq = (tid & 7) * 4;

    float acc00 = 0.f, acc01 = 0.f, acc10 = 0.f, acc11 = 0.f;

    for (int k0 = 0; k0 < 256; k0 += 32) {
        const int ch = ks * 256 + k0 + kq;
        const float4 p0 = *(const float4*)(fp + (size_t)(bm + row) * 512 + ch);
        const float4 p1 = *(const float4*)(fp + 131072 + (size_t)(bm + row) * 512 + ch);
        const float4 s4 = *(const float4*)(sf1 + ch);
        const float4 c4 = *(const float4*)(cf1 + ch);
        float4 av;
        av.x = fmaxf(fmaf(s4.x, p0.x + p1.x, c4.x), 0.f);
        av.y = fmaxf(fmaf(s4.y, p0.y + p1.y, c4.y), 0.f);
        av.z = fmaxf(fmaf(s4.z, p0.z + p1.z, c4.z), 0.f);
        av.w = fmaxf(fmaf(s4.w, p0.w + p1.w, c4.w), 0.f);
        const float4 wv = *(const float4*)(W + (size_t)(bn + row) * 512 + ch);
        __syncthreads();
        *(float4*)(&As[row][kq]) = av;
        *(float4*)(&Ws[row][kq]) = wv;
        __syncthreads();
        const float4* a0p = (const float4*)(&As[ml][0]);
        const float4* a1p = (const float4*)(&As[ml + 1][0]);
        const float4* b0p = (const float4*)(&Ws[nl][0]);
        const float4* b1p = (const float4*)(&Ws[nl + 1][0]);
        #pragma unroll
        for (int q = 0; q < 8; ++q) {
            const float4 a0 = a0p[q], a1 = a1p[q], b0 = b0p[q], b1 = b1p[q];
            acc00 = fmaf(a0.x, b0.x, fmaf(a0.y, b0.y, fmaf(a0.z, b0.z, fmaf(a0.w, b0.w, acc00))));
            acc01 = fmaf(a0.x, b1.x, fmaf(a0.y, b1.y, fmaf(a0.z, b1.z, fmaf(a0.w, b1.w, acc01))));
            acc10 = fmaf(a1.x, b0.x, fmaf(a1.y, b0.y, fmaf(a1.z, b0.z, fmaf(a1.w, b0.w, acc10))));
            acc11 = fmaf(a1.x, b1.x, fmaf(a1.y, b1.y, fmaf(a1.z, b1.z, fmaf(a1.w, b1.w, acc11))));
        }
    }
    float* q0 = P2 + (size_t)ks * 65536 + (size_t)(bm + ml) * 256 + bn + nl;
    q0[0] = acc00; q0[1] = acc01;
    float* q1 = q0 + 256;
    q1[0] = acc10; q1[1] = acc11;
}

// ---------------------------------------------------------------------------
// k_ep2: f2 = relu(sf2*(P2[0]+P2[1]) + cf2)
// ---------------------------------------------------------------------------
__global__ __launch_bounds__(256) void k_ep2(
    const float* __restrict__ P2, const float* __restrict__ sf2,
    const float* __restrict__ cf2, float* __restrict__ f2)
{
    const int i = blockIdx.x * 256 + threadIdx.x;
    const int n = i & 255;
    const float v = P2[i] + P2[65536 + i];
    f2[i] = fmaxf(fmaf(sf2[n], v, cf2[n]), 0.f);
}

// ---------------------------------------------------------------------------
// k_fc3: C = A*W^T + bias
// ---------------------------------------------------------------------------
__global__ __launch_bounds__(256) void k_fc3(
    const float* __restrict__ A, const float* __restrict__ W,
    const float* __restrict__ bias, float* __restrict__ C, int K, int Nc)
{
    __shared__ float As[32][36];
    __shared__ float Ws[32][36];

    const int tid = threadIdx.x;
    const int bm = blockIdx.x * 32, bn = blockIdx.y * 32;
    const int ml = (tid >> 4) * 2, nl = (tid & 15) * 2;
    const int row = tid >> 3, kq = (tid & 7) * 4;

    float acc00 = 0.f, acc01 = 0.f, acc10 = 0.f, acc11 = 0.f;

    for (int k0 = 0; k0 < K; k0 += 32) {
        const float4 av = *(const float4*)(A + (size_t)(bm + row) * K + k0 + kq);
        const float4 wv = *(const float4*)(W + (size_t)(bn + row) * K + k0 + kq);
        __syncthreads();
        *(float4*)(&As[row][kq]) = av;
        *(float4*)(&Ws[row][kq]) = wv;
        __syncthreads();
        const float4* a0p = (const float4*)(&As[ml][0]);
        const float4* a1p = (const float4*)(&As[ml + 1][0]);
        const float4* b0p = (const float4*)(&Ws[nl][0]);
        const float4* b1p = (const float4*)(&Ws[nl + 1][0]);
        #pragma unroll
        for (int q = 0; q < 8; ++q) {
            const float4 a0 = a0p[q], a1 = a1p[q], b0 = b0p[q], b1 = b1p[q];
            acc00 = fmaf(a0.x, b0.x, fmaf(a0.y, b0.y, fmaf(a0.z, b0.z, fmaf(a0.w, b0.w, acc00))));
            acc01 = fmaf(a0.x, b1.x, fmaf(a0.y, b1.y, fmaf(a0.z, b1.z, fmaf(a0.w, b1.w, acc01))));
            acc10 = fmaf(a1.x, b0.x, fmaf(a1.y, b0.y, fmaf(a1.z, b0.z, fmaf(a1.w, b0.w, acc10))));
            acc11 = fmaf(a1.x, b1.x, fmaf(a1.y, b1.y, fmaf(a1.z, b1.z, fmaf(a1.w, b1.w, acc11))));
        }
    }

    const int n0 = bn + nl, n1 = n0 + 1;
    float* cr0 = C + (size_t)(bm + ml) * Nc + n0;
    cr0[0] = acc00 + bias[n0]; cr0[1] = acc01 + bias[n1];
    float* cr1 = C + (size_t)(bm + ml + 1) * Nc + n0;
    cr1[0] = acc10 + bias[n0]; cr1[1] = acc11 + bias[n1];
}

// ---------------------------------------------------------------------------
extern "C" void kernel_launch(void* const* d_in, const int* in_sizes, int n_in,
                              void* d_out, int out_size, void* d_ws, size_t ws_size,
                              hipStream_t stream)
{
    const float* pts     = (const float*)d_in[0];
    const float* info    = (const float*)d_in[2];
    const float* w_info  = (const float*)d_in[3];
    const float* b_info  = (const float*)d_in[4];
    const float* g_info  = (const float*)d_in[5];
    const float* be_info = (const float*)d_in[6];
    const float* m_info  = (const float*)d_in[7];
    const float* v_info  = (const float*)d_in[8];
    const float* w2      = (const float*)d_in[9];
    const float* b2      = (const float*)d_in[10];
    const float* g2      = (const float*)d_in[11];
    const float* be2     = (const float*)d_in[12];
    const float* m2      = (const float*)d_in[13];
    const float* v2      = (const float*)d_in[14];
    const float* w3      = (const float*)d_in[15];
    const float* b3      = (const float*)d_in[16];
    const float* g3      = (const float*)d_in[17];
    const float* be3     = (const float*)d_in[18];
    const float* m3      = (const float*)d_in[19];
    const float* v3      = (const float*)d_in[20];
    const float* wf1     = (const float*)d_in[21];
    const float* bf1     = (const float*)d_in[22];
    const float* gf1     = (const float*)d_in[23];
    const float* bef1    = (const float*)d_in[24];
    const float* mf1     = (const float*)d_in[25];
    const float* vf1     = (const float*)d_in[26];
    const float* wf2     = (const float*)d_in[27];
    const float* bf2     = (const float*)d_in[28];
    const float* gf2     = (const float*)d_in[29];
    const float* bef2    = (const float*)d_in[30];
    const float* mf2     = (const float*)d_in[31];
    const float* vf2     = (const float*)d_in[32];
    const float* wf3     = (const float*)d_in[33];
    const float* bf3     = (const float*)d_in[34];

    float* ws = (float*)d_ws;
    unsigned short* h2h   = (unsigned short*)(ws + 491520);      // 524288 bf16
    unsigned short* h2l   = (unsigned short*)(ws + 753664);      // 524288 bf16
    float*          g     = ws + 1015808;                        // 262144
    unsigned short* Bh    = (unsigned short*)(ws + 1277952);     // 131072 bf16
    unsigned short* Bl    = (unsigned short*)(ws + 1343488);     // 131072 bf16
    float*          bias3 = ws + 1409024;                        // 1024
    float4*         w2q   = (float4*)(ws + 1410048);             // 8192
    float*          bias2 = ws + 1418240;                        // 128
    float4*         qTab4 = (float4*)(ws + 1418624);             // 256
    float*          sf1   = ws + 1418880;                        // 512
    float*          cf1   = ws + 1419392;                        // 512
    float*          sf2   = ws + 1419904;                        // 256
    float*          cf2   = ws + 1420160;                        // 256
    unsigned short* Bedge = (unsigned short*)(ws + 1420416);     // 1024 bf16 used
    float*          fp    = ws;                                  // [2][256][512] (free region)
    float*          P2    = ws + 262144;                         // [2][256][256]

    float* ret = (float*)d_out;            // [256, 800]
    float* f2  = ret + 256 * 800;          // [256, 256]

    k_pre<<<66, 256, 0, stream>>>(
        w3, b3, g3, be3, m3, v3,
        w2, b2, g2, be2, m2, v2,
        w_info, b_info, g_info, be_info, m_info, v_info,
        bf1, gf1, bef1, mf1, vf1,
        bf2, gf2, bef2, mf2, vf2,
        Bh, Bl, bias3, w2q, bias2, Bedge, qTab4, sf1, cf1, sf2, cf2);

    k_edgemm32<<<256, 512, 0, stream>>>(pts, info, Bedge, qTab4,
                                        w2q, bias2, h2h, h2l);

    k_s3<<<256, 256, 0, stream>>>(h2h, h2l, Bh, Bl, bias3, g);

    k_fc1p<<<dim3(8, 16, 2), 256, 0, stream>>>(g, wf1, fp);

    k_fc2p<<<dim3(8, 8, 2), 256, 0, stream>>>(fp, sf1, cf1, wf2, P2);

    k_ep2<<<256, 256, 0, stream>>>(P2, sf2, cf2, f2);

    k_fc3<<<dim3(8, 25), 256, 0, stream>>>(f2, wf3, bf3, ret, 256, 800);
}